// Round 1
// baseline (345.586 us; speedup 1.0000x reference)
//
#include <hip/hip_runtime.h>

// RWKV WKV forward — R5: 16-wave blocked scan + single-exp max-trick.
//
// Identity: with P=(num,den) scaled by 2^m, the step is the linear recurrence
// P' = 2^{tds} P + 2^{kts} (v,1), decay channel-constant => associative,
// segment compose = "decay by L, add local sum".
// Block = 1024 thr (16 waves) owns 64 contiguous channels; sequence processed
// in tiles of 128 steps (LDS double-buffered, global_load_lds width=16).
// Per tile: each wave w scans steps [w*8,(w+1)*8): phase A local sums
// (init m=-1e30,n=d=0), barrier, prefix-compose (w iterations), phase B
// replay from true incoming state + coalesced output stores. Wave 15's end
// state is the tile carry (double-buffered in LDS).
// Waves only touch their OWN k/v LDS rows, so barriers protect only
// summaries/carry; per-wave vmcnt drains cover the DMA.
//
// R5 changes vs R4 (349.3 us):
//  * NW 8->16: waves/SIMD 2->4 (latency hiding), per-wave serial depth per
//    tile 2x16 -> 2x8 steps.
//  * max-trick: ms=max(a,b) => one of exp(a-ms),exp(b-ms) is exactly 1;
//    compute e=exp2(-|a-b|) once + cndmask. Bit-identical, trans ops
//    per element 7 -> 4.

#define TILE 128
#define NW   16
#define SUB  (TILE / NW)   // 8

#define VMW0  asm volatile("s_waitcnt vmcnt(0)" ::: "memory")
#define VMW8  asm volatile("s_waitcnt vmcnt(8)" ::: "memory")
#define BARR  asm volatile("s_waitcnt lgkmcnt(0)\n\ts_barrier" ::: "memory")

__device__ __forceinline__ float ex2(float x)  { return __builtin_amdgcn_exp2f(x); }
__device__ __forceinline__ float rcpf(float x) { return __builtin_amdgcn_rcpf(x); }

__device__ __forceinline__ void dma16(const float* g, float* l) {
    __builtin_amdgcn_global_load_lds(
        (const __attribute__((address_space(1))) unsigned int*)g,
        (__attribute__((address_space(3))) unsigned int*)l, 16, 0, 0);
}

__global__ __launch_bounds__(1024)
void wkv_fwd(const float* __restrict__ td_in, const float* __restrict__ kin,
             const float* __restrict__ tf_in, const float* __restrict__ vin,
             const float* __restrict__ m0, const float* __restrict__ n0,
             const float* __restrict__ d0,
             float* __restrict__ out, float* __restrict__ m_out,
             float* __restrict__ n_out, float* __restrict__ dn_out,
             int B, int S, int H)
{
    __shared__ float kbuf[2][TILE][64];      // 64 KiB
    __shared__ float vbuf[2][TILE][64];      // 64 KiB
    __shared__ float smry[NW][3][64];        // 12 KiB
    __shared__ float cry[2][3][64];          // 1.5 KiB

    const int tid  = threadIdx.x;
    const int lane = tid & 63;
    const int w    = tid >> 6;               // wave id 0..15

    const int bpb = H >> 6;                  // blocks per batch
    const int b   = blockIdx.x / bpb;
    const int hb  = (blockIdx.x - b * bpb) << 6;
    const int h   = hb + lane;
    const int g   = b * H + h;

    constexpr float Cc = 1.4426950408889634f;   // log2(e)
    constexpr float IC = 0.6931471805599453f;   // ln(2)

    const float tds  = -ex2(td_in[h] * Cc) * Cc;  // per-step decay, log2 units
    const float tfs  = tf_in[h] * Cc;
    const float dseg = tds * (float)SUB;          // decay over one sub-segment

    if (w == 0) {                                 // tile-0 carry = init state
        cry[0][0][lane] = m0[g] * Cc;
        cry[0][1][lane] = n0[g];
        cry[0][2][lane] = d0[g];
    }

    const size_t base = (size_t)b * (size_t)S * (size_t)H + (size_t)hb;
    const float* gk = kin + base;
    const float* gv = vin + base;
    float*       go = out + base;

    const int sub = lane >> 4;                    // 0..3 (row within 4-row DMA)
    const int c4  = (lane & 15) << 2;             // channel offset (4 floats/lane)

    const int ntiles = S / TILE;

    // Prologue: DMA tile 0 into buffer 0 (each wave its own 8 rows of k and v).
    #pragma unroll
    for (int i = 0; i < SUB / 4; ++i) {
        const int r = w * SUB + i * 4;
        dma16(gk + (size_t)(r + sub) * H + c4, &kbuf[0][r][0]);
        dma16(gv + (size_t)(r + sub) * H + c4, &vbuf[0][r][0]);
    }

    float M = 0.f, N = 0.f, D = 0.f;

    for (int it = 0; it < ntiles; ++it) {
        const int p = it & 1;
        // Drain this tile's 4 DMA ops (per-wave). Steady state: 8 newer
        // output stores may remain outstanding -> vmcnt(8).
        if (it == 0) { VMW0; } else { VMW8; }
        BARR;                                   // publish smry/cry ordering

        if (it + 1 < ntiles) {                  // prefetch next tile
            const int np = p ^ 1;
            const size_t t1 = (size_t)(it + 1) * TILE;
            #pragma unroll
            for (int i = 0; i < SUB / 4; ++i) {
                const int r = w * SUB + i * 4;
                dma16(gk + (t1 + r + sub) * (size_t)H + c4, &kbuf[np][r][0]);
                dma16(gv + (t1 + r + sub) * (size_t)H + c4, &vbuf[np][r][0]);
            }
        }

        // ---- Phase A: local scan (state branch only), neutral init ----
        float lm = -1e30f, ln = 0.f, ldn = 0.f;
        #pragma unroll
        for (int j = 0; j < SUB; ++j) {
            const float kt  = kbuf[p][w * SUB + j][lane] * Cc;
            const float vt  = vbuf[p][w * SUB + j][lane];
            const float mpd = lm + tds;
            const float d   = mpd - kt;           // max-trick: one factor is 1
            const float e   = ex2(0.f - fabsf(d));
            const bool  c   = d >= 0.f;
            const float e1  = c ? 1.f : e;
            const float e2  = c ? e : 1.f;
            ln  = e1 * ln  + e2 * vt;
            ldn = e1 * ldn + e2;
            lm  = fmaxf(mpd, kt);
        }
        smry[w][0][lane] = lm;
        smry[w][1][lane] = ln;
        smry[w][2][lane] = ldn;
        BARR;

        // ---- Prefix compose: incoming state for this wave ----
        M = cry[p][0][lane];
        N = cry[p][1][lane];
        D = cry[p][2][lane];
        for (int j = 0; j < w; ++j) {
            const float Md = M + dseg;
            const float sm = smry[j][0][lane];
            const float d  = Md - sm;
            const float e  = ex2(0.f - fabsf(d));
            const bool  c  = d >= 0.f;
            const float a  = c ? 1.f : e;
            const float bb = c ? e : 1.f;
            N = a * N + bb * smry[j][1][lane];
            D = a * D + bb * smry[j][2][lane];
            M = fmaxf(Md, sm);
        }

        // ---- Phase B: replay with outputs (coalesced 256 B row stores) ----
        float* po = go + ((size_t)it * TILE + (size_t)w * SUB) * (size_t)H;
        #pragma unroll
        for (int j = 0; j < SUB; ++j) {
            const float kt  = kbuf[p][w * SUB + j][lane] * Cc;
            const float vt  = vbuf[p][w * SUB + j][lane];
            const float ktf = kt + tfs;
            const float dd  = M - ktf;
            const float eo  = ex2(0.f - fabsf(dd));
            const bool  co  = dd >= 0.f;
            const float e1o = co ? 1.f : eo;
            const float e2o = co ? eo : 1.f;
            po[(size_t)j * H + lane] =
                (e1o * N + e2o * vt) * rcpf(e1o * D + e2o);
            const float mpd = M + tds;
            const float ds_ = mpd - kt;
            const float es  = ex2(0.f - fabsf(ds_));
            const bool  cs  = ds_ >= 0.f;
            const float e1s = cs ? 1.f : es;
            const float e2s = cs ? es : 1.f;
            N = e1s * N + e2s * vt;
            D = e1s * D + e2s;
            M = fmaxf(mpd, kt);
        }

        if (w == NW - 1) {                      // tile carry (double-buffered)
            cry[p ^ 1][0][lane] = M;
            cry[p ^ 1][1][lane] = N;
            cry[p ^ 1][2][lane] = D;
        }
    }

    if (w == NW - 1) {                          // final states
        m_out[g]  = M * IC;
        n_out[g]  = N;
        dn_out[g] = D;
    }
}

// Safety fallback (serial per channel) for shapes the tiled kernel can't take.
__global__ __launch_bounds__(64)
void wkv_fwd_serial(const float* __restrict__ td_in, const float* __restrict__ kin,
                    const float* __restrict__ tf_in, const float* __restrict__ vin,
                    const float* __restrict__ m0, const float* __restrict__ n0,
                    const float* __restrict__ d0,
                    float* __restrict__ out, float* __restrict__ m_out,
                    float* __restrict__ n_out, float* __restrict__ dn_out,
                    int B, int S, int H)
{
    const int g = blockIdx.x * 64 + threadIdx.x;
    if (g >= B * H) return;
    const int b = g / H;
    const int h = g - b * H;
    constexpr float Cc = 1.4426950408889634f, IC = 0.6931471805599453f;
    const float tds = -ex2(td_in[h] * Cc) * Cc;
    const float tfs = tf_in[h] * Cc;
    float M = m0[g] * Cc, N = n0[g], D = d0[g];
    const size_t base = (size_t)b * S * H + h;
    for (int t = 0; t < S; ++t) {
        const float kt  = kin[base + (size_t)t * H] * Cc;
        const float vt  = vin[base + (size_t)t * H];
        const float ktf = kt + tfs;
        const float mo  = fmaxf(M, ktf);
        const float e1o = ex2(M - mo), e2o = ex2(ktf - mo);
        out[base + (size_t)t * H] = (e1o * N + e2o * vt) * rcpf(e1o * D + e2o);
        const float mpd = M + tds;
        const float ms  = fmaxf(mpd, kt);
        const float e1s = ex2(mpd - ms), e2s = ex2(kt - ms);
        N = e1s * N + e2s * vt;
        D = e1s * D + e2s;
        M = ms;
    }
    m_out[g] = M * IC; n_out[g] = N; dn_out[g] = D;
}

extern "C" void kernel_launch(void* const* d_in, const int* in_sizes, int n_in,
                              void* d_out, int out_size, void* d_ws, size_t ws_size,
                              hipStream_t stream)
{
    const float* time_decay = (const float*)d_in[0];
    const float* key        = (const float*)d_in[1];
    const float* time_first = (const float*)d_in[2];
    const float* value      = (const float*)d_in[3];
    const float* max_state  = (const float*)d_in[4];
    const float* num_state  = (const float*)d_in[5];
    const float* den_state  = (const float*)d_in[6];

    const int H  = in_sizes[0];
    const int BH = in_sizes[4];
    const int B  = BH / H;
    const int S  = in_sizes[1] / BH;

    float* out    = (float*)d_out;
    float* m_out  = out + (size_t)B * (size_t)S * (size_t)H;
    float* n_out  = m_out + BH;
    float* dn_out = n_out + BH;

    if ((H % 64 == 0) && (S % TILE == 0)) {
        const int grid = BH / 64;               // 256 blocks, 1/CU
        wkv_fwd<<<grid, 1024, 0, stream>>>(time_decay, key, time_first, value,
                                           max_state, num_state, den_state,
                                           out, m_out, n_out, dn_out, B, S, H);
    } else {
        const int grid = (BH + 63) / 64;
        wkv_fwd_serial<<<grid, 64, 0, stream>>>(time_decay, key, time_first, value,
                                                max_state, num_state, den_state,
                                                out, m_out, n_out, dn_out, B, S, H);
    }
}

// Round 2
// 338.812 us; speedup vs baseline: 1.0200x; 1.0200x over previous
//
#include <hip/hip_runtime.h>

// RWKV WKV forward — R6: prefix-compose phase B (full ILP) + 1 barrier/tile.
//
// Identity: with P=(num,den) scaled by 2^m, the step is the linear recurrence
// P' = 2^{tds} P + 2^{kts} (v,1), decay channel-constant => associative.
// Block = 1024 thr (16 waves) owns 64 contiguous channels; sequence processed
// in tiles of 128 steps (LDS double-buffered, global_load_lds width=16).
// Per tile: wave w scans steps [w*8,(w+1)*8):
//   Phase A: local scan (neutral init), keeping per-step prefixes
//            L_j=(lm,ln,ld) and kt,vt in REGISTERS; publish totals to smry.
//   BARRIER (the only one per tile; smry/cry double-buffered by parity).
//   Compose: incoming state = cry composed with smry[0..w-1].
//   Wave 15: carry = Dec^8(incoming) ⊕ own totals, written immediately
//            (phase B is off the inter-tile critical path).
//   Phase B: out_j from S_j = Dec^j(In) ⊕ L_j — one-shot compose per step,
//            ALL steps independent (no serial chain), zero LDS reads.
// k/v LDS rows are wave-private (each wave DMAs and reads only its own 8
// rows), so per-wave vmcnt drains cover the DMA; no top-of-loop barrier.
//
// R6 vs R5 (dispatch 133us, VALUBusy 34%, hbm 25%): removes phase-B serial
// chain + 16 of 32 barriers; identical math (compose == replay exactly).

#define TILE 128
#define NW   16
#define SUB  (TILE / NW)   // 8

#define VMW0  asm volatile("s_waitcnt vmcnt(0)" ::: "memory")
#define VMW8  asm volatile("s_waitcnt vmcnt(8)" ::: "memory")
#define BARR  asm volatile("s_waitcnt lgkmcnt(0)\n\ts_barrier" ::: "memory")

__device__ __forceinline__ float ex2(float x)  { return __builtin_amdgcn_exp2f(x); }
__device__ __forceinline__ float rcpf(float x) { return __builtin_amdgcn_rcpf(x); }

__device__ __forceinline__ void dma16(const float* g, float* l) {
    __builtin_amdgcn_global_load_lds(
        (const __attribute__((address_space(1))) unsigned int*)g,
        (__attribute__((address_space(3))) unsigned int*)l, 16, 0, 0);
}

__global__ __launch_bounds__(1024)
void wkv_fwd(const float* __restrict__ td_in, const float* __restrict__ kin,
             const float* __restrict__ tf_in, const float* __restrict__ vin,
             const float* __restrict__ m0, const float* __restrict__ n0,
             const float* __restrict__ d0,
             float* __restrict__ out, float* __restrict__ m_out,
             float* __restrict__ n_out, float* __restrict__ dn_out,
             int B, int S, int H)
{
    __shared__ float kbuf[2][TILE][64];      // 64 KiB
    __shared__ float vbuf[2][TILE][64];      // 64 KiB
    __shared__ float smry[2][NW][3][64];     // 24 KiB (double-buffered)
    __shared__ float cry[2][3][64];          // 1.5 KiB

    const int tid  = threadIdx.x;
    const int lane = tid & 63;
    const int w    = tid >> 6;               // wave id 0..15

    const int bpb = H >> 6;                  // blocks per batch
    const int b   = blockIdx.x / bpb;
    const int hb  = (blockIdx.x - b * bpb) << 6;
    const int h   = hb + lane;
    const int g   = b * H + h;

    constexpr float Cc = 1.4426950408889634f;   // log2(e)
    constexpr float IC = 0.6931471805599453f;   // ln(2)

    const float tds  = -ex2(td_in[h] * Cc) * Cc;  // per-step decay, log2 units
    const float tfs  = tf_in[h] * Cc;
    const float dseg = tds * (float)SUB;          // decay over one sub-segment

    if (w == 0) {                                 // tile-0 carry = init state
        cry[0][0][lane] = m0[g] * Cc;
        cry[0][1][lane] = n0[g];
        cry[0][2][lane] = d0[g];
    }

    const size_t base = (size_t)b * (size_t)S * (size_t)H + (size_t)hb;
    const float* gk = kin + base;
    const float* gv = vin + base;
    float*       go = out + base;

    const int sub = lane >> 4;                    // 0..3 (row within 4-row DMA)
    const int c4  = (lane & 15) << 2;             // channel offset (4 floats/lane)

    const int ntiles = S / TILE;

    // Prologue: DMA tile 0 into buffer 0 (each wave its own 8 rows of k and v).
    #pragma unroll
    for (int i = 0; i < SUB / 4; ++i) {
        const int r = w * SUB + i * 4;
        dma16(gk + (size_t)(r + sub) * H + c4, &kbuf[0][r][0]);
        dma16(gv + (size_t)(r + sub) * H + c4, &vbuf[0][r][0]);
    }

    float fM = 0.f, fN = 0.f, fD = 0.f;           // wave15 final state

    for (int it = 0; it < ntiles; ++it) {
        const int p = it & 1;
        // Drain this tile's 4 DMA ops (per-wave, oldest in queue). Steady
        // state: 8 newer output stores may remain outstanding -> vmcnt(8).
        if (it == 0) { VMW0; } else { VMW8; }

        if (it + 1 < ntiles) {                  // prefetch next tile
            const int np = p ^ 1;
            const size_t t1 = (size_t)(it + 1) * TILE;
            #pragma unroll
            for (int i = 0; i < SUB / 4; ++i) {
                const int r = w * SUB + i * 4;
                dma16(gk + (t1 + r + sub) * (size_t)H + c4, &kbuf[np][r][0]);
                dma16(gv + (t1 + r + sub) * (size_t)H + c4, &vbuf[np][r][0]);
            }
        }

        // ---- Phase A: local scan, prefixes kept in registers ----
        float kt[SUB], vt[SUB];
        float plm[SUB - 1], pln[SUB - 1], pld[SUB - 1];
        float lm = -1e30f, ln = 0.f, ld = 0.f;
        #pragma unroll
        for (int j = 0; j < SUB; ++j) {
            kt[j] = kbuf[p][w * SUB + j][lane] * Cc;
            vt[j] = vbuf[p][w * SUB + j][lane];
            const float mpd = lm + tds;
            const float d   = mpd - kt[j];        // max-trick: one factor is 1
            const float e   = ex2(-fabsf(d));
            const bool  c   = d >= 0.f;
            const float e1  = c ? 1.f : e;
            const float e2  = c ? e : 1.f;
            ln  = e1 * ln  + e2 * vt[j];
            ld  = e1 * ld  + e2;
            lm  = fmaxf(mpd, kt[j]);
            if (j < SUB - 1) { plm[j] = lm; pln[j] = ln; pld[j] = ld; }
        }
        smry[p][w][0][lane] = lm;
        smry[p][w][1][lane] = ln;
        smry[p][w][2][lane] = ld;
        BARR;                                   // the only barrier per tile

        // ---- Prefix compose: incoming state for this wave ----
        float M = cry[p][0][lane];
        float N = cry[p][1][lane];
        float D = cry[p][2][lane];
        for (int j = 0; j < w; ++j) {
            const float Md = M + dseg;
            const float sm = smry[p][j][0][lane];
            const float d  = Md - sm;
            const float e  = ex2(-fabsf(d));
            const bool  c  = d >= 0.f;
            const float a  = c ? 1.f : e;
            const float bb = c ? e : 1.f;
            N = a * N + bb * smry[p][j][1][lane];
            D = a * D + bb * smry[p][j][2][lane];
            M = fmaxf(Md, sm);
        }

        // ---- Wave 15: tile carry via one compose (off the output path) ----
        if (w == NW - 1) {
            const float Md = M + dseg;
            const float d  = Md - lm;
            const float e  = ex2(-fabsf(d));
            const bool  c  = d >= 0.f;
            const float a  = c ? 1.f : e;
            const float bb = c ? e : 1.f;
            fN = a * N + bb * ln;
            fD = a * D + bb * ld;
            fM = fmaxf(Md, lm);
            cry[p ^ 1][0][lane] = fM;
            cry[p ^ 1][1][lane] = fN;
            cry[p ^ 1][2][lane] = fD;
        }

        // ---- Phase B: outputs via one-shot compose — all steps independent -
        float* po = go + ((size_t)it * TILE + (size_t)w * SUB) * (size_t)H;
        {   // j = 0: state before step 0 is exactly (M,N,D)
            const float ktf = kt[0] + tfs;
            const float dd  = M - ktf;
            const float eo  = ex2(-fabsf(dd));
            const bool  co  = dd >= 0.f;
            const float e1o = co ? 1.f : eo;
            const float e2o = co ? eo : 1.f;
            po[lane] = (e1o * N + e2o * vt[0]) * rcpf(fmaf(e1o, D, e2o));
        }
        float Md = M;
        #pragma unroll
        for (int j = 1; j < SUB; ++j) {
            Md += tds;                            // M + j*tds (cheap 4cy chain)
            const float sm = plm[j - 1];
            const float dl = Md - sm;
            const float e  = ex2(-fabsf(dl));
            const bool  c  = dl >= 0.f;
            const float a  = c ? 1.f : e;
            const float bb = c ? e : 1.f;
            const float Nc = a * N + bb * pln[j - 1];
            const float Dc = a * D + bb * pld[j - 1];
            const float Mc = fmaxf(Md, sm);
            const float ktf = kt[j] + tfs;
            const float dd  = Mc - ktf;
            const float eo  = ex2(-fabsf(dd));
            const bool  co  = dd >= 0.f;
            const float e1o = co ? 1.f : eo;
            const float e2o = co ? eo : 1.f;
            po[(size_t)j * H + lane] =
                (e1o * Nc + e2o * vt[j]) * rcpf(fmaf(e1o, Dc, e2o));
        }
    }

    if (w == NW - 1) {                          // final states
        m_out[g]  = fM * IC;
        n_out[g]  = fN;
        dn_out[g] = fD;
    }
}

// Safety fallback (serial per channel) for shapes the tiled kernel can't take.
__global__ __launch_bounds__(64)
void wkv_fwd_serial(const float* __restrict__ td_in, const float* __restrict__ kin,
                    const float* __restrict__ tf_in, const float* __restrict__ vin,
                    const float* __restrict__ m0, const float* __restrict__ n0,
                    const float* __restrict__ d0,
                    float* __restrict__ out, float* __restrict__ m_out,
                    float* __restrict__ n_out, float* __restrict__ dn_out,
                    int B, int S, int H)
{
    const int g = blockIdx.x * 64 + threadIdx.x;
    if (g >= B * H) return;
    const int b = g / H;
    const int h = g - b * H;
    constexpr float Cc = 1.4426950408889634f, IC = 0.6931471805599453f;
    const float tds = -ex2(td_in[h] * Cc) * Cc;
    const float tfs = tf_in[h] * Cc;
    float M = m0[g] * Cc, N = n0[g], D = d0[g];
    const size_t base = (size_t)b * S * H + h;
    for (int t = 0; t < S; ++t) {
        const float kt  = kin[base + (size_t)t * H] * Cc;
        const float vt  = vin[base + (size_t)t * H];
        const float ktf = kt + tfs;
        const float mo  = fmaxf(M, ktf);
        const float e1o = ex2(M - mo), e2o = ex2(ktf - mo);
        out[base + (size_t)t * H] = (e1o * N + e2o * vt) * rcpf(e1o * D + e2o);
        const float mpd = M + tds;
        const float ms  = fmaxf(mpd, kt);
        const float e1s = ex2(mpd - ms), e2s = ex2(kt - ms);
        N = e1s * N + e2s * vt;
        D = e1s * D + e2s;
        M = ms;
    }
    m_out[g] = M * IC; n_out[g] = N; dn_out[g] = D;
}

extern "C" void kernel_launch(void* const* d_in, const int* in_sizes, int n_in,
                              void* d_out, int out_size, void* d_ws, size_t ws_size,
                              hipStream_t stream)
{
    const float* time_decay = (const float*)d_in[0];
    const float* key        = (const float*)d_in[1];
    const float* time_first = (const float*)d_in[2];
    const float* value      = (const float*)d_in[3];
    const float* max_state  = (const float*)d_in[4];
    const float* num_state  = (const float*)d_in[5];
    const float* den_state  = (const float*)d_in[6];

    const int H  = in_sizes[0];
    const int BH = in_sizes[4];
    const int B  = BH / H;
    const int S  = in_sizes[1] / BH;

    float* out    = (float*)d_out;
    float* m_out  = out + (size_t)B * (size_t)S * (size_t)H;
    float* n_out  = m_out + BH;
    float* dn_out = n_out + BH;

    if ((H % 64 == 0) && (S % TILE == 0)) {
        const int grid = BH / 64;               // 256 blocks, 1/CU
        wkv_fwd<<<grid, 1024, 0, stream>>>(time_decay, key, time_first, value,
                                           max_state, num_state, den_state,
                                           out, m_out, n_out, dn_out, B, S, H);
    } else {
        const int grid = (BH + 63) / 64;
        wkv_fwd_serial<<<grid, 64, 0, stream>>>(time_decay, key, time_first, value,
                                                max_state, num_state, den_state,
                                                out, m_out, n_out, dn_out, B, S, H);
    }
}

// Round 3
// 336.964 us; speedup vs baseline: 1.0256x; 1.0055x over previous
//
#include <hip/hip_runtime.h>

// RWKV WKV forward — R7: register-resident tiles, issue-early prefetch,
// no LDS k/v staging.
//
// Identity: with P=(num,den) scaled by 2^m, the step is the linear recurrence
// P' = 2^{tds} P + 2^{kts} (v,1), decay channel-constant => associative.
// Block = 1024 thr (16 waves) owns 64 contiguous channels (lane = channel);
// sequence in tiles of 128 steps, wave w owns steps [w*8,(w+1)*8).
//
// Memory discipline (the R7 change): k/v rows are loaded DIRECTLY to
// registers (coalesced 256 B/row, 4 B/lane), double-buffered across tiles by
// compile-time register-set alternation (2x unrolled tile loop). The loads
// for tile it+1 are issued at the TOP of tile it, before any wait on tile
// it's data — the compiler's fine-grained vmcnt waits only on the current
// set while the next set stays in flight across the (lgkmcnt-only) barrier.
// This replaces R6's drain-then-issue global_load_lds pipeline, whose
// per-tile queue-empty bursts pinned the period at memory service latency
// (19.5k cy/tile ~ 2 TB/s).
//
// Per tile: Phase A local scan (neutral init), prefixes in registers;
// publish totals to smry; ONE barrier; prefix-compose (fixed-trip unrolled,
// wave-uniform guard, ds_reads batched); wave 15 writes carry immediately;
// Phase B outputs via one-shot compose — all 8 steps independent.

#define TILE 128
#define NW   16
#define SUB  (TILE / NW)   // 8

#define BARR  asm volatile("s_waitcnt lgkmcnt(0)\n\ts_barrier" ::: "memory")

__device__ __forceinline__ float ex2(float x)  { return __builtin_amdgcn_exp2f(x); }
__device__ __forceinline__ float rcpf(float x) { return __builtin_amdgcn_rcpf(x); }

__global__ __launch_bounds__(1024)
void wkv_fwd(const float* __restrict__ td_in, const float* __restrict__ kin,
             const float* __restrict__ tf_in, const float* __restrict__ vin,
             const float* __restrict__ m0, const float* __restrict__ n0,
             const float* __restrict__ d0,
             float* __restrict__ out, float* __restrict__ m_out,
             float* __restrict__ n_out, float* __restrict__ dn_out,
             int B, int S, int H)
{
    __shared__ float smry[2][NW][3][64];     // 24 KiB (double-buffered)
    __shared__ float cry[2][3][64];          // 1.5 KiB

    const int tid  = threadIdx.x;
    const int lane = tid & 63;
    const int w    = tid >> 6;               // wave id 0..15

    const int bpb = H >> 6;                  // blocks per batch
    const int b   = blockIdx.x / bpb;
    const int hb  = (blockIdx.x - b * bpb) << 6;
    const int h   = hb + lane;
    const int g   = b * H + h;

    constexpr float Cc = 1.4426950408889634f;   // log2(e)
    constexpr float IC = 0.6931471805599453f;   // ln(2)

    const float tds  = -ex2(td_in[h] * Cc) * Cc;  // per-step decay, log2 units
    const float tfs  = tf_in[h] * Cc;
    const float dseg = tds * (float)SUB;          // decay over one sub-segment

    if (w == 0) {                                 // tile-0 carry = init state
        cry[0][0][lane] = m0[g] * Cc;
        cry[0][1][lane] = n0[g];
        cry[0][2][lane] = d0[g];
    }

    const size_t base = (size_t)b * (size_t)S * (size_t)H + (size_t)hb;
    const float* gk = kin + base;
    const float* gv = vin + base;
    float*       go = out + base;

    const int ntiles = S / TILE;

    float fM = 0.f, fN = 0.f, fD = 0.f;           // wave15 final state

    // Register double-buffers for this wave's 8 (k,v) rows.
    float ka[SUB], va[SUB], kb[SUB], vb[SUB];

    // Prologue: issue loads for tile 0 into set A (coalesced 256 B rows).
    {
        const size_t t0 = (size_t)w * SUB;
        #pragma unroll
        for (int j = 0; j < SUB; ++j) {
            ka[j] = gk[(t0 + j) * (size_t)H + lane];
            va[j] = gv[(t0 + j) * (size_t)H + lane];
        }
    }

    auto body = [&](int it, float (&ck)[SUB], float (&cv)[SUB],
                    float (&nk)[SUB], float (&nv)[SUB])
                __attribute__((always_inline)) -> void {
        // ---- Issue-early: prefetch tile it+1 into the other register set.
        // No wait precedes this; the compiler's auto-vmcnt before first use
        // of ck/cv waits only on the older (current) loads.
        if (it + 1 < ntiles) {
            const size_t t1 = (size_t)(it + 1) * TILE + (size_t)w * SUB;
            #pragma unroll
            for (int j = 0; j < SUB; ++j) {
                nk[j] = gk[(t1 + j) * (size_t)H + lane];
                nv[j] = gv[(t1 + j) * (size_t)H + lane];
            }
        }

        const int p = it & 1;

        // ---- Phase A: local scan, prefixes kept in registers ----
        float kt[SUB], vt[SUB];
        float plm[SUB - 1], pln[SUB - 1], pld[SUB - 1];
        float lm = -1e30f, ln = 0.f, ld = 0.f;
        #pragma unroll
        for (int j = 0; j < SUB; ++j) {
            kt[j] = ck[j] * Cc;
            vt[j] = cv[j];
            const float mpd = lm + tds;
            const float d   = mpd - kt[j];        // max-trick: one factor is 1
            const float e   = ex2(-fabsf(d));
            const bool  c   = d >= 0.f;
            const float e1  = c ? 1.f : e;
            const float e2  = c ? e : 1.f;
            ln  = e1 * ln  + e2 * vt[j];
            ld  = e1 * ld  + e2;
            lm  = fmaxf(mpd, kt[j]);
            if (j < SUB - 1) { plm[j] = lm; pln[j] = ln; pld[j] = ld; }
        }
        smry[p][w][0][lane] = lm;
        smry[p][w][1][lane] = ln;
        smry[p][w][2][lane] = ld;
        BARR;                                   // the only barrier per tile
                                                // (lgkmcnt only — vmem loads
                                                //  stay in flight across it)

        // ---- Prefix compose: fixed-trip unrolled, wave-uniform guard ----
        // ds_reads are unconditional (batched up-front); compose executes
        // w iterations via a uniform s_cbranch — no per-iteration ds latency.
        float M = cry[p][0][lane];
        float N = cry[p][1][lane];
        float D = cry[p][2][lane];
        #pragma unroll
        for (int j = 0; j < NW - 1; ++j) {
            const float sm = smry[p][j][0][lane];
            const float sn = smry[p][j][1][lane];
            const float sd = smry[p][j][2][lane];
            if (j < w) {
                const float Md = M + dseg;
                const float d  = Md - sm;
                const float e  = ex2(-fabsf(d));
                const bool  c  = d >= 0.f;
                const float a  = c ? 1.f : e;
                const float bb = c ? e : 1.f;
                N = a * N + bb * sn;
                D = a * D + bb * sd;
                M = fmaxf(Md, sm);
            }
        }

        // ---- Wave 15: tile carry via one compose (off the output path) ----
        if (w == NW - 1) {
            const float Md = M + dseg;
            const float d  = Md - lm;
            const float e  = ex2(-fabsf(d));
            const bool  c  = d >= 0.f;
            const float a  = c ? 1.f : e;
            const float bb = c ? e : 1.f;
            fN = a * N + bb * ln;
            fD = a * D + bb * ld;
            fM = fmaxf(Md, lm);
            cry[p ^ 1][0][lane] = fM;
            cry[p ^ 1][1][lane] = fN;
            cry[p ^ 1][2][lane] = fD;
        }

        // ---- Phase B: outputs via one-shot compose — all steps independent -
        float* po = go + ((size_t)it * TILE + (size_t)w * SUB) * (size_t)H;
        {   // j = 0: state before step 0 is exactly (M,N,D)
            const float ktf = kt[0] + tfs;
            const float dd  = M - ktf;
            const float eo  = ex2(-fabsf(dd));
            const bool  co  = dd >= 0.f;
            const float e1o = co ? 1.f : eo;
            const float e2o = co ? eo : 1.f;
            po[lane] = (e1o * N + e2o * vt[0]) * rcpf(fmaf(e1o, D, e2o));
        }
        float Md = M;
        #pragma unroll
        for (int j = 1; j < SUB; ++j) {
            Md += tds;                            // M + j*tds (cheap chain)
            const float sm = plm[j - 1];
            const float dl = Md - sm;
            const float e  = ex2(-fabsf(dl));
            const bool  c  = dl >= 0.f;
            const float a  = c ? 1.f : e;
            const float bb = c ? e : 1.f;
            const float Nc = a * N + bb * pln[j - 1];
            const float Dc = a * D + bb * pld[j - 1];
            const float Mc = fmaxf(Md, sm);
            const float ktf = kt[j] + tfs;
            const float dd  = Mc - ktf;
            const float eo  = ex2(-fabsf(dd));
            const bool  co  = dd >= 0.f;
            const float e1o = co ? 1.f : eo;
            const float e2o = co ? eo : 1.f;
            po[(size_t)j * H + lane] =
                (e1o * Nc + e2o * vt[j]) * rcpf(fmaf(e1o, Dc, e2o));
        }
    };

    int it = 0;
    for (; it + 1 < ntiles; it += 2) {
        body(it,     ka, va, kb, vb);
        body(it + 1, kb, vb, ka, va);
    }
    if (it < ntiles) body(it, ka, va, kb, vb);

    if (w == NW - 1) {                          // final states
        m_out[g]  = fM * IC;
        n_out[g]  = fN;
        dn_out[g] = fD;
    }
}

// Safety fallback (serial per channel) for shapes the tiled kernel can't take.
__global__ __launch_bounds__(64)
void wkv_fwd_serial(const float* __restrict__ td_in, const float* __restrict__ kin,
                    const float* __restrict__ tf_in, const float* __restrict__ vin,
                    const float* __restrict__ m0, const float* __restrict__ n0,
                    const float* __restrict__ d0,
                    float* __restrict__ out, float* __restrict__ m_out,
                    float* __restrict__ n_out, float* __restrict__ dn_out,
                    int B, int S, int H)
{
    const int g = blockIdx.x * 64 + threadIdx.x;
    if (g >= B * H) return;
    const int b = g / H;
    const int h = g - b * H;
    constexpr float Cc = 1.4426950408889634f, IC = 0.6931471805599453f;
    const float tds = -ex2(td_in[h] * Cc) * Cc;
    const float tfs = tf_in[h] * Cc;
    float M = m0[g] * Cc, N = n0[g], D = d0[g];
    const size_t base = (size_t)b * S * H + h;
    for (int t = 0; t < S; ++t) {
        const float kt  = kin[base + (size_t)t * H] * Cc;
        const float vt  = vin[base + (size_t)t * H];
        const float ktf = kt + tfs;
        const float mo  = fmaxf(M, ktf);
        const float e1o = ex2(M - mo), e2o = ex2(ktf - mo);
        out[base + (size_t)t * H] = (e1o * N + e2o * vt) * rcpf(e1o * D + e2o);
        const float mpd = M + tds;
        const float ms  = fmaxf(mpd, kt);
        const float e1s = ex2(mpd - ms), e2s = ex2(kt - ms);
        N = e1s * N + e2s * vt;
        D = e1s * D + e2s;
        M = ms;
    }
    m_out[g] = M * IC; n_out[g] = N; dn_out[g] = D;
}

extern "C" void kernel_launch(void* const* d_in, const int* in_sizes, int n_in,
                              void* d_out, int out_size, void* d_ws, size_t ws_size,
                              hipStream_t stream)
{
    const float* time_decay = (const float*)d_in[0];
    const float* key        = (const float*)d_in[1];
    const float* time_first = (const float*)d_in[2];
    const float* value      = (const float*)d_in[3];
    const float* max_state  = (const float*)d_in[4];
    const float* num_state  = (const float*)d_in[5];
    const float* den_state  = (const float*)d_in[6];

    const int H  = in_sizes[0];
    const int BH = in_sizes[4];
    const int B  = BH / H;
    const int S  = in_sizes[1] / BH;

    float* out    = (float*)d_out;
    float* m_out  = out + (size_t)B * (size_t)S * (size_t)H;
    float* n_out  = m_out + BH;
    float* dn_out = n_out + BH;

    if ((H % 64 == 0) && (S % TILE == 0)) {
        const int grid = BH / 64;               // 256 blocks, 1/CU
        wkv_fwd<<<grid, 1024, 0, stream>>>(time_decay, key, time_first, value,
                                           max_state, num_state, den_state,
                                           out, m_out, n_out, dn_out, B, S, H);
    } else {
        const int grid = (BH + 63) / 64;
        wkv_fwd_serial<<<grid, 64, 0, stream>>>(time_decay, key, time_first, value,
                                                max_state, num_state, den_state,
                                                out, m_out, n_out, dn_out, B, S, H);
    }
}